// Round 9
// baseline (3409.015 us; speedup 1.0000x reference)
//
#include <hip/hip_runtime.h>

// GridCellRouter: N=4096*4096 cells, 16 iterations of
//   accum[idx[i]] += cur[i];  cur[i] = accum[i] - cur[i]
//
// Recurrence (verified R4): c_{t+1} = S c_t + c_{t-1}, answer = c16 + c15.
// BSGS (verified R8): answer = sum_{k=0..16} alpha_k S^k r,
//   alpha = [1,8,36,84,210,252,462,330,495,220,286,78,91,14,15,1,1].
//   3 applies of S (B1,B2,B3) + 4 applies of T=S^4 (Horner, w_q fused).
// R11 (verified R8-round): two-phase line-granular permute (route+acc)
//   replaced the 1 GB/pass random gather; 3133 us measured.
//
// R16: compose_idx was the measured top item (2 x 317 us, FETCH 1.04 GB =
// random-line ceiling). Replace both composes with a bucketed 3-phase
// line-granular gather (same cure as route/acc, deterministic by carrying i):
//   P1 cmp_route:   chunk reads idx seq; route rec (i, v&16383) by v-bucket
//                   via LDS cursors (1024x1024 count+scan layout).
//   P2 cmp_gather:  per v-bucket: stage a[16K window] in LDS; rec.y -> a[v]
//                   (in-place seq read-modify-write).
//   P3 cmp_scatter: per 16K out-window: thread t walks bucket t's run,
//                   scatters to LDS window by i&16383 (each slot exactly
//                   once), writes window sequentially.
// Apply path (route_op/acc_op/b1/s1/s2/s3) byte-identical to the verified
// R11 kernel. ALL indices masked/clamped -> no OOB possible.

#define N_CELLS (1 << 24)

#define BKT_BITS 14
#define NBKT (N_CELLS >> BKT_BITS)        // 1024 buckets
#define DPB (1 << BKT_BITS)               // 16384 dsts per bucket
#define BKT_MASK (DPB - 1)
#define IDX_MASK (N_CELLS - 1)
#define G1 256                            // wgs in b1/route
#define EDGES_PER_WG (N_CELLS / G1)       // 65536
#define BT 1024                           // threads in b1/route

#define CCH 1024                          // compose chunks (= NBKT)
#define CCHSZ (N_CELLS / CCH)             // 16384 elements per chunk

typedef unsigned uv4 __attribute__((ext_vector_type(4)));
typedef float fv4 __attribute__((ext_vector_type(4)));
typedef unsigned long long u64;

__device__ __align__(16) unsigned g_T[2][NBKT * G1];       // (bucket,wg) offsets, applies
__device__ __align__(16) unsigned g_bktcnt[2][NBKT];       // bucket totals, applies
__device__ __align__(16) unsigned g_S[2][NBKT + 4];        // bucket starts (excl), applies
__device__ __align__(16) uint2 g_rec[N_CELLS];             // records (shared: compose, applies)
__device__ __align__(16) unsigned g_C[NBKT * CCH];         // compose counts  [b][w]
__device__ __align__(16) unsigned g_O[NBKT * CCH];         // compose offsets [b][w]
__device__ __align__(16) unsigned g_CB[NBKT];              // compose bucket totals
__device__ __align__(16) unsigned g_CS[NBKT + 4];          // compose bucket starts
__device__ __align__(16) int g_idx2[N_CELLS];              // idx o idx
__device__ __align__(16) int g_idx4[N_CELLS];              // idx2 o idx2
__device__ __align__(16) float gB1[N_CELLS];               // S r
__device__ __align__(16) float gB2[N_CELLS];               // S^2 r
__device__ __align__(16) float gB3[N_CELLS];               // S^3 r
__device__ __align__(16) float gH[N_CELLS];                // Horner ping buffer

// ==================== compose machinery (3-phase gather) ====================

// cmp_cnt: count a-values per (bucket, chunk) at 16K-chunk granularity
__global__ void __launch_bounds__(BT) cmp_cnt(const int* __restrict__ ext, int mode) {
    const int* __restrict__ a = mode ? g_idx2 : ext;
    __shared__ unsigned h[NBKT];
    int t = threadIdx.x;
    h[t] = 0u;
    __syncthreads();
    const uv4* p = reinterpret_cast<const uv4*>(a) + (size_t)blockIdx.x * (CCHSZ / 4);
    for (int k = 0; k < CCHSZ / 4 / BT; ++k) {   // 4 iters
        uv4 v = __builtin_nontemporal_load(&p[k * BT + t]);
        atomicAdd(&h[(v.x & IDX_MASK) >> BKT_BITS], 1u);
        atomicAdd(&h[(v.y & IDX_MASK) >> BKT_BITS], 1u);
        atomicAdd(&h[(v.z & IDX_MASK) >> BKT_BITS], 1u);
        atomicAdd(&h[(v.w & IDX_MASK) >> BKT_BITS], 1u);
    }
    __syncthreads();
    g_C[(size_t)t * CCH + blockIdx.x] = h[t];
}

// cmp_s1: bucket totals (one wg per bucket; row of 1024 contiguous)
__global__ void cmp_s1() {
    __shared__ unsigned sd[256];
    int t = threadIdx.x;
    uint4 v = reinterpret_cast<const uint4*>(g_C + (size_t)blockIdx.x * CCH)[t];
    sd[t] = v.x + v.y + v.z + v.w;
    __syncthreads();
    for (int off = 128; off > 0; off >>= 1) {
        if (t < off) sd[t] += sd[t + off];
        __syncthreads();
    }
    if (t == 0) g_CB[blockIdx.x] = sd[0];
}

// cmp_s2: exclusive scan of g_CB[1024] -> g_CS (proven 256xuint4 pattern)
__global__ void cmp_s2() {
    __shared__ unsigned s[256];
    int t = threadIdx.x;
    uint4 v = reinterpret_cast<const uint4*>(g_CB)[t];
    unsigned local = v.x + v.y + v.z + v.w;
    s[t] = local;
    __syncthreads();
    for (int off = 1; off < 256; off <<= 1) {
        unsigned add = (t >= off) ? s[t - off] : 0u;
        __syncthreads();
        s[t] += add;
        __syncthreads();
    }
    unsigned run = s[t] - local;
    uint4 o;
    o.x = run; run += v.x;
    o.y = run; run += v.y;
    o.z = run; run += v.z;
    o.w = run;
    reinterpret_cast<uint4*>(g_CS)[t] = o;
    if (t == 0) g_CS[NBKT] = (unsigned)N_CELLS;
}

// cmp_s3: per-bucket exclusive scan of 1024 chunk counts + base -> g_O
__global__ void __launch_bounds__(BT) cmp_s3() {
    __shared__ unsigned s[BT];
    int t = threadIdx.x;
    unsigned c = g_C[(size_t)blockIdx.x * CCH + t];
    s[t] = c;
    __syncthreads();
    for (int off = 1; off < BT; off <<= 1) {
        unsigned add = (t >= off) ? s[t - off] : 0u;
        __syncthreads();
        s[t] += add;
        __syncthreads();
    }
    g_O[(size_t)blockIdx.x * CCH + t] = g_CS[blockIdx.x] + s[t] - c;
}

// P1: route records (i, v&16383) by v-bucket via per-(bucket,chunk) cursors.
// Cursor race order is irrelevant: records carry i explicitly.
__global__ void __launch_bounds__(BT) cmp_route(const int* __restrict__ ext, int mode) {
    const int* __restrict__ a = mode ? g_idx2 : ext;
    __shared__ unsigned cur[NBKT];
    int t = threadIdx.x;
    cur[t] = g_O[(size_t)t * CCH + blockIdx.x];
    __syncthreads();
    const uv4* p = reinterpret_cast<const uv4*>(a) + (size_t)blockIdx.x * (CCHSZ / 4);
    unsigned base_i = blockIdx.x * CCHSZ;
    for (int k = 0; k < CCHSZ / 4 / BT; ++k) {   // 4 iters
        uv4 v = __builtin_nontemporal_load(&p[k * BT + t]);
        unsigned i0 = base_i + (k * BT + t) * 4;
        unsigned e, pos;
        e = v.x & IDX_MASK; pos = atomicAdd(&cur[e >> BKT_BITS], 1u) & IDX_MASK;
        g_rec[pos] = make_uint2(i0, e & BKT_MASK);
        e = v.y & IDX_MASK; pos = atomicAdd(&cur[e >> BKT_BITS], 1u) & IDX_MASK;
        g_rec[pos] = make_uint2(i0 + 1, e & BKT_MASK);
        e = v.z & IDX_MASK; pos = atomicAdd(&cur[e >> BKT_BITS], 1u) & IDX_MASK;
        g_rec[pos] = make_uint2(i0 + 2, e & BKT_MASK);
        e = v.w & IDX_MASK; pos = atomicAdd(&cur[e >> BKT_BITS], 1u) & IDX_MASK;
        g_rec[pos] = make_uint2(i0 + 3, e & BKT_MASK);
    }
}

// P2: per v-bucket: stage a[b*16K..+16K) in LDS; rec.y = a[v] in place.
__global__ void __launch_bounds__(BT) cmp_gather(const int* __restrict__ ext, int mode) {
    const int* __restrict__ a = mode ? g_idx2 : ext;
    __shared__ unsigned lds[DPB];   // 64 KB
    int t = threadIdx.x;
    unsigned b = blockIdx.x;
    for (int j = t; j < DPB; j += BT) lds[j] = (unsigned)a[(size_t)b * DPB + j];
    __syncthreads();
    unsigned start = g_CS[b];
    unsigned end = g_CS[b + 1];
    if (end > (unsigned)N_CELLS) end = (unsigned)N_CELLS;
    if (start > end) start = end;
    for (unsigned e = start + t; e < end; e += BT) {
        uint2 q = g_rec[e];
        g_rec[e] = make_uint2(q.x, lds[q.y & BKT_MASK]);
    }
}

// P3: per 16K out-window w: thread t walks bucket t's run for w, scatters
// into LDS window by i&16383 (each slot exactly once), writes seq.
__global__ void __launch_bounds__(BT) cmp_scatter(int mode) {
    int* __restrict__ o = mode ? g_idx4 : g_idx2;
    __shared__ unsigned win[DPB];   // 64 KB
    int t = threadIdx.x;
    unsigned w = blockIdx.x;
    for (int j = t; j < DPB; j += BT) win[j] = 0u;
    __syncthreads();
    unsigned start = g_O[(size_t)t * CCH + w];
    unsigned end = (w == CCH - 1) ? g_CS[t + 1] : g_O[(size_t)t * CCH + w + 1];
    if (start > (unsigned)N_CELLS) start = (unsigned)N_CELLS;
    if (end > (unsigned)N_CELLS) end = (unsigned)N_CELLS;
    for (unsigned e = start; e < end; ++e) {
        uint2 q = g_rec[e];
        win[q.x & BKT_MASK] = q.y;
    }
    __syncthreads();
    for (int j = t; j < DPB; j += BT) o[(size_t)w * DPB + j] = (int)win[j];
}

// ==================== apply machinery (verified R11) ====================

// b1: count edges per (bucket, wg). NBKT == BT == 1024.
__global__ void __launch_bounds__(BT) b1_count(const int* __restrict__ ext, int set) {
    const int* __restrict__ idx = set ? g_idx4 : ext;
    __shared__ unsigned h[NBKT];
    int t = threadIdx.x;
    h[t] = 0u;
    __syncthreads();
    const uv4* p = reinterpret_cast<const uv4*>(idx) + (size_t)blockIdx.x * (EDGES_PER_WG / 4);
    for (int k = 0; k < EDGES_PER_WG / 4 / BT; ++k) {   // 16 iters
        uv4 v = __builtin_nontemporal_load(&p[k * BT + t]);
        atomicAdd(&h[(v.x & IDX_MASK) >> BKT_BITS], 1u);
        atomicAdd(&h[(v.y & IDX_MASK) >> BKT_BITS], 1u);
        atomicAdd(&h[(v.z & IDX_MASK) >> BKT_BITS], 1u);
        atomicAdd(&h[(v.w & IDX_MASK) >> BKT_BITS], 1u);
    }
    __syncthreads();
    g_T[set][(size_t)t * G1 + blockIdx.x] = h[t];
}

// s1: bucket totals (one wg per bucket, row of 256 is contiguous)
__global__ void s1_sums(int set) {
    __shared__ unsigned sd[256];
    int t = threadIdx.x;
    sd[t] = g_T[set][(size_t)blockIdx.x * G1 + t];
    __syncthreads();
    for (int off = 128; off > 0; off >>= 1) {
        if (t < off) sd[t] += sd[t + off];
        __syncthreads();
    }
    if (t == 0) g_bktcnt[set][blockIdx.x] = sd[0];
}

// s2: exclusive scan of g_bktcnt[1024] -> g_S. 256 threads x uint4.
__global__ void s2_scan(int set) {
    __shared__ unsigned s[256];
    int t = threadIdx.x;
    uint4 v = reinterpret_cast<const uint4*>(g_bktcnt[set])[t];
    unsigned local = v.x + v.y + v.z + v.w;
    s[t] = local;
    __syncthreads();
    for (int off = 1; off < 256; off <<= 1) {
        unsigned add = (t >= off) ? s[t - off] : 0u;
        __syncthreads();
        s[t] += add;
        __syncthreads();
    }
    unsigned run = s[t] - local;
    uint4 o;
    o.x = run; run += v.x;
    o.y = run; run += v.y;
    o.z = run; run += v.z;
    o.w = run;
    reinterpret_cast<uint4*>(g_S[set])[t] = o;
    if (t == 0) g_S[set][NBKT] = (unsigned)N_CELLS;
}

// s3: within-bucket exclusive scan of 256 wg counts + bucket base
__global__ void s3_offsets(int set) {
    __shared__ unsigned s[256];
    int t = threadIdx.x;
    unsigned v = g_T[set][(size_t)blockIdx.x * G1 + t];
    s[t] = v;
    __syncthreads();
    for (int off = 1; off < 256; off <<= 1) {
        unsigned add = (t >= off) ? s[t - off] : 0u;
        __syncthreads();
        s[t] += add;
        __syncthreads();
    }
    g_T[set][(size_t)blockIdx.x * G1 + t] = g_S[set][blockIdx.x] + s[t] - v;
}

// pointer selector (host can't take addresses of __device__ statics)
__device__ __forceinline__ float* sel_buf(int which, const float* r, float* dout) {
    switch (which) {
        case 0: return (float*)r;
        case 1: return gB1;
        case 2: return gB2;
        case 3: return gB3;
        case 4: return gH;
        default: return dout;
    }
}

// route: phase 1 of an apply. Sequential NT reads of ct-chunk + idxN-chunk;
// scatter self-describing records (value, dst14) to per-(wg,bucket) runs.
__global__ void __launch_bounds__(BT) route_op(const float* __restrict__ rin,
                                               float* __restrict__ dout,
                                               const int* __restrict__ ext,
                                               int ct_sel, int set) {
    const int* __restrict__ idx = set ? g_idx4 : ext;
    const float* __restrict__ ct = sel_buf(ct_sel, rin, dout);
    __shared__ unsigned cur[NBKT];
    int t = threadIdx.x;
    cur[t] = g_T[set][(size_t)t * G1 + blockIdx.x];   // t < 1024 == NBKT
    __syncthreads();
    const uv4* ip = reinterpret_cast<const uv4*>(idx) + (size_t)blockIdx.x * (EDGES_PER_WG / 4);
    const fv4* cp = reinterpret_cast<const fv4*>(ct) + (size_t)blockIdx.x * (EDGES_PER_WG / 4);
    for (int k = 0; k < EDGES_PER_WG / 4 / BT; ++k) {   // 16 iters
        uv4 v = __builtin_nontemporal_load(&ip[k * BT + t]);
        fv4 c = __builtin_nontemporal_load(&cp[k * BT + t]);
        unsigned e, p;
        e = v.x & IDX_MASK; p = atomicAdd(&cur[e >> BKT_BITS], 1u) & IDX_MASK;
        g_rec[p] = make_uint2(__float_as_uint(c.x), e & BKT_MASK);
        e = v.y & IDX_MASK; p = atomicAdd(&cur[e >> BKT_BITS], 1u) & IDX_MASK;
        g_rec[p] = make_uint2(__float_as_uint(c.y), e & BKT_MASK);
        e = v.z & IDX_MASK; p = atomicAdd(&cur[e >> BKT_BITS], 1u) & IDX_MASK;
        g_rec[p] = make_uint2(__float_as_uint(c.z), e & BKT_MASK);
        e = v.w & IDX_MASK; p = atomicAdd(&cur[e >> BKT_BITS], 1u) & IDX_MASK;
        g_rec[p] = make_uint2(__float_as_uint(c.w), e & BKT_MASK);
    }
}

// acc: phase 2 of an apply. One wg per bucket; sequential record read;
// LDS float-atomic accumulate over 16384 dsts; epilogue writes
//   out[row] = acc[row] + (fuse ? a0*r + a1*B1 + a2*B2 + a3*B3 : 0)
__global__ void __launch_bounds__(512) acc_op(const float* __restrict__ rin,
                                              float* __restrict__ dout,
                                              int out_sel, int set, int fuse,
                                              float a0, float a1, float a2, float a3) {
    __shared__ float acc[DPB];   // 64 KB -> 2 wg/CU, 16 waves/CU
    int t = threadIdx.x;
    unsigned b = blockIdx.x;
    float* __restrict__ out = sel_buf(out_sel, rin, dout);
    unsigned base = g_S[set][b];
    unsigned end = g_S[set][b + 1];
    if (end > (unsigned)N_CELLS) end = (unsigned)N_CELLS;
    if (base > end) base = end;
    fv4* acc4 = reinterpret_cast<fv4*>(acc);
    fv4 z = (fv4)(0.0f);
    for (int k = 0; k < DPB / 4 / 512; ++k) acc4[k * 512 + t] = z;   // 8 iters
    __syncthreads();
    const u64* __restrict__ rec = reinterpret_cast<const u64*>(g_rec);
    unsigned e = base + t;
    for (; e + 1536 < end; e += 2048) {
        u64 q0 = __builtin_nontemporal_load(&rec[e]);
        u64 q1 = __builtin_nontemporal_load(&rec[e + 512]);
        u64 q2 = __builtin_nontemporal_load(&rec[e + 1024]);
        u64 q3 = __builtin_nontemporal_load(&rec[e + 1536]);
        atomicAdd(&acc[(unsigned)(q0 >> 32) & BKT_MASK], __uint_as_float((unsigned)q0));
        atomicAdd(&acc[(unsigned)(q1 >> 32) & BKT_MASK], __uint_as_float((unsigned)q1));
        atomicAdd(&acc[(unsigned)(q2 >> 32) & BKT_MASK], __uint_as_float((unsigned)q2));
        atomicAdd(&acc[(unsigned)(q3 >> 32) & BKT_MASK], __uint_as_float((unsigned)q3));
    }
    for (; e < end; e += 512) {
        u64 q = __builtin_nontemporal_load(&rec[e]);
        atomicAdd(&acc[(unsigned)(q >> 32) & BKT_MASK], __uint_as_float((unsigned)q));
    }
    __syncthreads();
    size_t rowbase = (size_t)b * (DPB / 4);
    fv4* out4 = reinterpret_cast<fv4*>(out) + rowbase;
    if (fuse) {
        const fv4* r4 = reinterpret_cast<const fv4*>(rin) + rowbase;
        const fv4* p1 = reinterpret_cast<const fv4*>(gB1) + rowbase;
        const fv4* p2 = reinterpret_cast<const fv4*>(gB2) + rowbase;
        const fv4* p3 = reinterpret_cast<const fv4*>(gB3) + rowbase;
        for (int k = 0; k < DPB / 4 / 512; ++k) {
            int j = k * 512 + t;
            fv4 a = acc4[j];
            fv4 x = __builtin_nontemporal_load(&r4[j]);
            fv4 y = __builtin_nontemporal_load(&p1[j]);
            fv4 u = __builtin_nontemporal_load(&p2[j]);
            fv4 w = __builtin_nontemporal_load(&p3[j]);
            a += a0 * x + a1 * y + a2 * u + a3 * w;
            __builtin_nontemporal_store(a, &out4[j]);
        }
    } else {
        for (int k = 0; k < DPB / 4 / 512; ++k) {
            int j = k * 512 + t;
            __builtin_nontemporal_store(acc4[j], &out4[j]);
        }
    }
}

extern "C" void kernel_launch(void* const* d_in, const int* in_sizes, int n_in,
                              void* d_out, int out_size, void* d_ws, size_t ws_size,
                              hipStream_t stream) {
    const int* idx = (const int*)d_in[1];
    const float* r = (const float*)d_in[0];   // read-only
    float* out = (float*)d_out;

    // ---- build S layout (set 0) ----
    b1_count<<<G1, BT, 0, stream>>>(idx, 0);
    s1_sums<<<NBKT, 256, 0, stream>>>(0);
    s2_scan<<<1, 256, 0, stream>>>(0);
    s3_offsets<<<NBKT, 256, 0, stream>>>(0);

    // ---- compose1: idx2 = idx o idx (3-phase line-granular gather) ----
    cmp_cnt<<<CCH, BT, 0, stream>>>(idx, 0);
    cmp_s1<<<NBKT, 256, 0, stream>>>();
    cmp_s2<<<1, 256, 0, stream>>>();
    cmp_s3<<<NBKT, BT, 0, stream>>>();
    cmp_route<<<CCH, BT, 0, stream>>>(idx, 0);
    cmp_gather<<<NBKT, BT, 0, stream>>>(idx, 0);
    cmp_scatter<<<CCH, BT, 0, stream>>>(0);

    // ---- compose2: idx4 = idx2 o idx2 ----
    cmp_cnt<<<CCH, BT, 0, stream>>>(idx, 1);
    cmp_s1<<<NBKT, 256, 0, stream>>>();
    cmp_s2<<<1, 256, 0, stream>>>();
    cmp_s3<<<NBKT, BT, 0, stream>>>();
    cmp_route<<<CCH, BT, 0, stream>>>(idx, 1);
    cmp_gather<<<NBKT, BT, 0, stream>>>(idx, 1);
    cmp_scatter<<<CCH, BT, 0, stream>>>(1);

    // ---- build T layout (set 1, from idx4) ----
    b1_count<<<G1, BT, 0, stream>>>(idx, 1);
    s1_sums<<<NBKT, 256, 0, stream>>>(1);
    s2_scan<<<1, 256, 0, stream>>>(1);
    s3_offsets<<<NBKT, 256, 0, stream>>>(1);

    // ---- baby steps: B1 = S r, B2 = S B1, B3 = S B2 ----
    route_op<<<G1, BT, 0, stream>>>(r, out, idx, 0, 0);
    acc_op<<<NBKT, 512, 0, stream>>>(r, out, 1, 0, 0, 0.f, 0.f, 0.f, 0.f);
    route_op<<<G1, BT, 0, stream>>>(r, out, idx, 1, 0);
    acc_op<<<NBKT, 512, 0, stream>>>(r, out, 2, 0, 0, 0.f, 0.f, 0.f, 0.f);
    route_op<<<G1, BT, 0, stream>>>(r, out, idx, 2, 0);
    acc_op<<<NBKT, 512, 0, stream>>>(r, out, 3, 0, 0, 0.f, 0.f, 0.f, 0.f);

    // ---- giant steps: Horner over T = S^4 ----
    // alpha (k=0..16): 1,8,36,84,210,252,462,330,495,220,286,78,91,14,15,1,1
    // g3 = T r  + w3 : (91,14,15,1)      -> gH
    route_op<<<G1, BT, 0, stream>>>(r, out, idx, 0, 1);
    acc_op<<<NBKT, 512, 0, stream>>>(r, out, 4, 1, 1, 91.f, 14.f, 15.f, 1.f);
    // g2 = T g3 + w2 : (495,220,286,78)  -> d_out
    route_op<<<G1, BT, 0, stream>>>(r, out, idx, 4, 1);
    acc_op<<<NBKT, 512, 0, stream>>>(r, out, 5, 1, 1, 495.f, 220.f, 286.f, 78.f);
    // g1 = T g2 + w1 : (210,252,462,330) -> gH
    route_op<<<G1, BT, 0, stream>>>(r, out, idx, 5, 1);
    acc_op<<<NBKT, 512, 0, stream>>>(r, out, 4, 1, 1, 210.f, 252.f, 462.f, 330.f);
    // g0 = T g1 + w0 : (1,8,36,84)       -> d_out  (= answer)
    route_op<<<G1, BT, 0, stream>>>(r, out, idx, 4, 1);
    acc_op<<<NBKT, 512, 0, stream>>>(r, out, 5, 1, 1, 1.f, 8.f, 36.f, 84.f);
}